// Round 1
// 129.332 us; speedup vs baseline: 1.0113x; 1.0113x over previous
//
#include <hip/hip_runtime.h>
#include <hip/hip_bf16.h>

// GaussianAttention: S=512, B=32, T=1024, E=512, Q=128. f32 in / f32 out.
// out = [ new_context (S*B*E) | mean (S*B) ].
//
// K0: wave per (s,b): d0=q.w0, d1=q.w1 shuffle-reduced; mraw/std stored [B,S].
// K1: 32 blocks x 64 thr: barrier-free scan (serial-8 + wave shuffle scan).
// K2 (R7): 256 threads, s-split halves (waves 0-1 -> s rows 0..7, waves 2-3 ->
//     rows 8..15) sharing one lds_w; 4 waves/SIMD (was 2) + 1-deep prefetch of
//     the next emb row + nontemporal out stores (out is write-once; keep the
//     hot emb window resident in per-XCD L2). Weights < exp(-20) dropped
//     (tail < 1e-5 vs measured floor 0.03).
//
// NOTE (R6 post-mortem): do NOT fuse K0+K1 into one block-per-b kernel —
// 32 blocks = 2.5% occupancy, 53 us (latency-bound serial dot chain).
// Dispatch-gap saving (~2 us) never pays for lost grid parallelism.

#define S_DIM 512
#define B_DIM 32
#define T_DIM 1024
#define E_DIM 512
#define Q_DIM 128
#define WIN_CUT 20.0f
#define CH 16     // s-values per K2 block
#define TSEG 64   // t-segment (union window is ~14-40 rows, 64 covers it)

typedef float v4f __attribute__((ext_vector_type(4)));

// K0: 4 waves/block, one (s,b) pair per wave. grid = S*B/4 = 4096.
__global__ __launch_bounds__(256) void dot_kernel(
    const float* __restrict__ query,  // [S,B,Q]
    const float* __restrict__ W,      // [2,Q]
    const float* __restrict__ bias,   // [2]
    float* __restrict__ ws_mraw,      // [B,S]
    float* __restrict__ ws_std)       // [B,S]
{
    const int wave = threadIdx.x >> 6;
    const int lane = threadIdx.x & 63;
    const int pair = blockIdx.x * 4 + wave;       // = s*B + b
    const float2* qp = (const float2*)(query + (size_t)pair * Q_DIM);
    float2 v = qp[lane];
    float d0 = v.x * W[2 * lane]         + v.y * W[2 * lane + 1];
    float d1 = v.x * W[Q_DIM + 2 * lane] + v.y * W[Q_DIM + 2 * lane + 1];
    #pragma unroll
    for (int off = 32; off; off >>= 1) {
        d0 += __shfl_down(d0, off);
        d1 += __shfl_down(d1, off);
    }
    if (lane == 0) {
        int s = pair / B_DIM, b = pair % B_DIM;
        ws_mraw[(size_t)b * S_DIM + s] = expf(d0 + bias[0]);
        ws_std[(size_t)b * S_DIM + s]  = expf(d1 + bias[1]);
    }
}

// K1: one block (64 thr) per b. lane handles 8 consecutive s. No barriers.
__global__ __launch_bounds__(64) void scan_kernel(
    const float* __restrict__ ws_mraw,   // [B,S]
    const float* __restrict__ position,  // [S,B]
    float* __restrict__ ws_mean,         // [B,S]
    float* __restrict__ out_mean)        // [S,B] f32
{
    const int b = blockIdx.x;
    const int lane = threadIdx.x;
    const float4* src = (const float4*)(ws_mraw + (size_t)b * S_DIM + lane * 8);
    float4 x0 = src[0], x1 = src[1];
    float v[8] = {x0.x, x0.y, x0.z, x0.w, x1.x, x1.y, x1.z, x1.w};
    float pre[8], run = 0.f;
    #pragma unroll
    for (int j = 0; j < 8; ++j) { run += v[j]; pre[j] = run; }
    float tot = run, sc = tot;
    #pragma unroll
    for (int off = 1; off < 64; off <<= 1) {
        float u = __shfl_up(sc, off);
        if (lane >= off) sc += u;
    }
    float excl = sc - tot;
    #pragma unroll
    for (int j = 0; j < 8; ++j) {
        int s = lane * 8 + j;
        float m = position[(size_t)s * B_DIM + b] + (excl + pre[j]) * 0.05f;
        ws_mean[(size_t)b * S_DIM + s] = m;
        out_mean[(size_t)s * B_DIM + b] = m;
    }
}

// K2: grid (S/CH, B), 256 threads. Two s-halves of 8 rows share each emb row.
__global__ __launch_bounds__(256) void ctx_kernel(
    const float* __restrict__ emb,     // [T,B,E]
    const float* __restrict__ mask,    // [T,B]
    const float* __restrict__ ws_mean, // [B,S]
    const float* __restrict__ ws_std,  // [B,S]
    float* __restrict__ out)           // [S,B,E]
{
    __shared__ float lds_w[TSEG * CH];
    __shared__ float lds_mean[CH], lds_std[CH];
    __shared__ float lds_lo[CH], lds_hi[CH];
    __shared__ int s_tlo, s_thi;
    const int c = blockIdx.x, b = blockIdx.y;
    const int s0 = c * CH;
    const int tid = threadIdx.x;
    const int half = tid >> 7;       // 0: rows s0..s0+7, 1: rows s0+8..s0+15
    const int htid = tid & 127;      // E/4 lane within half

    if (tid < CH) {
        float m  = ws_mean[(size_t)b * S_DIM + s0 + tid];
        float sd = ws_std[(size_t)b * S_DIM + s0 + tid];
        lds_mean[tid] = m;
        lds_std[tid]  = sd;
        float r = __fsqrt_rn(WIN_CUT / sd);   // sqrt in parallel, not in tid0 chain
        lds_lo[tid] = m - r;
        lds_hi[tid] = m + r;
    }
    __syncthreads();
    if (tid == 0) {
        float lo = 1e30f, hi = -1e30f;
        #pragma unroll
        for (int i = 0; i < CH; ++i) {
            lo = fminf(lo, lds_lo[i]);
            hi = fmaxf(hi, lds_hi[i]);
        }
        int tlo = (int)floorf(lo);
        if (tlo < 0) tlo = 0; if (tlo > T_DIM - 1) tlo = T_DIM - 1;
        int thi = (int)ceilf(hi);
        if (thi > T_DIM - 1) thi = T_DIM - 1; if (thi < tlo) thi = tlo;
        s_tlo = tlo; s_thi = thi;
    }
    __syncthreads();
    const int tlo = s_tlo, thi = s_thi;

    v4f acc[8];
    #pragma unroll
    for (int i = 0; i < 8; ++i) acc[i] = (v4f)0.f;

    for (int tseg = tlo; tseg <= thi; tseg += TSEG) {
        // Weights: all 256 threads; thread covers toff = tid>>2, 4 i-slots.
        {
            const int toff = tid >> 2;
            const int ibase = (tid & 3) * 4;
            const int t = tseg + toff;
            float mv = 0.f;
            if (t <= thi) mv = mask[(size_t)t * B_DIM + b];
            v4f w;
            #pragma unroll
            for (int j = 0; j < 4; ++j) {
                int i = ibase + j;
                float d = lds_mean[i] - (float)t;
                w[j] = (t <= thi) ? __expf(-lds_std[i] * d * d) * mv : 0.f;
            }
            *(v4f*)(lds_w + toff * CH + ibase) = w;
        }
        __syncthreads();
        const int tend = (thi < tseg + TSEG - 1) ? thi : (tseg + TSEG - 1);
        const float* wbase = lds_w + half * 8;
        v4f v = ((const v4f*)(emb + ((size_t)tseg * B_DIM + b) * E_DIM))[htid];
        for (int t = tseg; t <= tend; ++t) {
            // 1-deep prefetch: next row load issues before this row's FMAs.
            const int tn = (t < tend) ? t + 1 : t;
            v4f vn = ((const v4f*)(emb + ((size_t)tn * B_DIM + b) * E_DIM))[htid];
            const float* wrow = wbase + (t - tseg) * CH;
            #pragma unroll
            for (int i = 0; i < 8; ++i) {
                float w = wrow[i];
                acc[i] += w * v;
            }
            v = vn;
        }
        __syncthreads();
    }
    #pragma unroll
    for (int i = 0; i < 8; ++i) {
        v4f* dst = (v4f*)(out + ((size_t)(s0 + half * 8 + i) * B_DIM + b) * E_DIM);
        __builtin_nontemporal_store(acc[i], dst + htid);  // write-once, bypass L2
    }
}

extern "C" void kernel_launch(void* const* d_in, const int* in_sizes, int n_in,
                              void* d_out, int out_size, void* d_ws, size_t ws_size,
                              hipStream_t stream) {
    const float* query = (const float*)d_in[0]; // [S,B,Q]
    const float* emb   = (const float*)d_in[1]; // [T,B,E]
    const float* mask  = (const float*)d_in[2]; // [T,B]
    const float* pos   = (const float*)d_in[3]; // [S,B]
    const float* W     = (const float*)d_in[4]; // [2,Q]
    const float* bias  = (const float*)d_in[5]; // [2]

    float* out_ctx  = (float*)d_out;                            // S*B*E
    float* out_mean = out_ctx + (size_t)S_DIM * B_DIM * E_DIM;  // S*B

    float* ws_mraw = (float*)d_ws;                      // [B,S]
    float* ws_std  = ws_mraw + (size_t)S_DIM * B_DIM;   // [B,S]
    float* ws_mean = ws_std  + (size_t)S_DIM * B_DIM;   // [B,S] (192 KiB total)

    dot_kernel<<<(S_DIM * B_DIM) / 4, 256, 0, stream>>>(query, W, bias, ws_mraw, ws_std);
    scan_kernel<<<B_DIM, 64, 0, stream>>>(ws_mraw, pos, ws_mean, out_mean);
    ctx_kernel<<<dim3(S_DIM / CH, B_DIM), 256, 0, stream>>>(emb, mask, ws_mean, ws_std, out_ctx);
}

// Round 2
// 125.556 us; speedup vs baseline: 1.0417x; 1.0301x over previous
//
#include <hip/hip_runtime.h>
#include <hip/hip_bf16.h>

// GaussianAttention: S=512, B=32, T=1024, E=512, Q=128. f32 in / f32 out.
// out = [ new_context (S*B*E) | mean (S*B) ].
//
// K0: wave per (s,b): d0=q.w0, d1=q.w1 shuffle-reduced; mraw/std stored [B,S].
// K2 (R8): K1's scan FUSED in — each (c,b) block recomputes the cumsum prefix
//     via a 256-thread block-scan of mraw[b,0..511] (2 KB, L2-resident, fully
//     grid-parallel — NOT the R6 32-block fusion trap). 2 dispatches total.
//     256 threads, s-split halves (waves 0-1 -> rows 0..7, waves 2-3 -> rows
//     8..15) share one lds_w; 1-deep prefetch of next emb row; nontemporal
//     out stores (write-once, keep hot emb window in per-XCD L2).
//     Weights < exp(-20) dropped (tail < 1e-5 vs measured floor 0.03).
//
// NOTE (R6 post-mortem): do NOT fuse K0 in as block-per-b — 32 blocks = 2.5%
// occupancy, 53 us latency-bound. Grid-parallel redundant scan (this version)
// is the right fusion shape.
// NOTE (R7 post-mortem): K2 occupancy 2->4 waves/SIMD + prefetch = only
// -1.5 us => kernels are NOT the bulk of dur_us; harness poison fills
// (268 MB @ ~41 us each, 81% HBM peak) dominate the timed region.

#define S_DIM 512
#define B_DIM 32
#define T_DIM 1024
#define E_DIM 512
#define Q_DIM 128
#define WIN_CUT 20.0f
#define CH 16     // s-values per K2 block
#define TSEG 64   // t-segment (union window is ~14-40 rows, 64 covers it)

typedef float v4f __attribute__((ext_vector_type(4)));

// K0: 4 waves/block, one (s,b) pair per wave. grid = S*B/4 = 4096.
__global__ __launch_bounds__(256) void dot_kernel(
    const float* __restrict__ query,  // [S,B,Q]
    const float* __restrict__ W,      // [2,Q]
    const float* __restrict__ bias,   // [2]
    float* __restrict__ ws_mraw,      // [B,S]
    float* __restrict__ ws_std)       // [B,S]
{
    const int wave = threadIdx.x >> 6;
    const int lane = threadIdx.x & 63;
    const int pair = blockIdx.x * 4 + wave;       // = s*B + b
    const float2* qp = (const float2*)(query + (size_t)pair * Q_DIM);
    float2 v = qp[lane];
    float d0 = v.x * W[2 * lane]         + v.y * W[2 * lane + 1];
    float d1 = v.x * W[Q_DIM + 2 * lane] + v.y * W[Q_DIM + 2 * lane + 1];
    #pragma unroll
    for (int off = 32; off; off >>= 1) {
        d0 += __shfl_down(d0, off);
        d1 += __shfl_down(d1, off);
    }
    if (lane == 0) {
        int s = pair / B_DIM, b = pair % B_DIM;
        ws_mraw[(size_t)b * S_DIM + s] = expf(d0 + bias[0]);
        ws_std[(size_t)b * S_DIM + s]  = expf(d1 + bias[1]);
    }
}

// K2: grid (S/CH, B), 256 threads. Scan fused; two s-halves share emb rows.
__global__ __launch_bounds__(256) void ctx_kernel(
    const float* __restrict__ emb,      // [T,B,E]
    const float* __restrict__ mask,     // [T,B]
    const float* __restrict__ ws_mraw,  // [B,S]
    const float* __restrict__ ws_std,   // [B,S]
    const float* __restrict__ position, // [S,B]
    float* __restrict__ out,            // [S,B,E]
    float* __restrict__ out_mean)       // [S,B]
{
    __shared__ float lds_w[TSEG * CH];
    __shared__ float lds_mean[CH], lds_std[CH];
    __shared__ float lds_lo[CH], lds_hi[CH];
    __shared__ float lds_wt[4];
    __shared__ int s_tlo, s_thi;
    const int c = blockIdx.x, b = blockIdx.y;
    const int s0 = c * CH;
    const int tid = threadIdx.x;
    const int wv = tid >> 6, lane = tid & 63;
    const int half = tid >> 7;       // 0: rows s0..s0+7, 1: rows s0+8..s0+15
    const int htid = tid & 127;      // E/4 lane within half

    // ---- fused scan (was K1): inclusive cumsum of mraw[b, 0..511] ----
    // Thread tid owns elements 2tid, 2tid+1. Wave-scan of pair sums, then
    // cross-wave offsets via lds_wt. incl(2tid+1) = woff+sc; incl(2tid) -= f2.y.
    float2 f2 = ((const float2*)(ws_mraw + (size_t)b * S_DIM))[tid];
    float sc = f2.x + f2.y;
    #pragma unroll
    for (int off = 1; off < 64; off <<= 1) {
        float u = __shfl_up(sc, off);
        if (lane >= off) sc += u;
    }
    if (lane == 63) lds_wt[wv] = sc;
    __syncthreads();
    float woff = 0.f;
    #pragma unroll
    for (int w = 0; w < 4; ++w) woff += (w < wv) ? lds_wt[w] : 0.f;
    if (tid >= (s0 >> 1) && tid < ((s0 + CH) >> 1)) {
        const int i0 = tid * 2 - s0;              // 0,2,..,14
        const int sa = s0 + i0, sb = sa + 1;
        float m0 = position[(size_t)sa * B_DIM + b] + (woff + sc - f2.y) * 0.05f;
        float m1 = position[(size_t)sb * B_DIM + b] + (woff + sc) * 0.05f;
        float sd0 = ws_std[(size_t)b * S_DIM + sa];
        float sd1 = ws_std[(size_t)b * S_DIM + sb];
        lds_mean[i0] = m0;  lds_mean[i0 + 1] = m1;
        lds_std[i0]  = sd0; lds_std[i0 + 1]  = sd1;
        float r0 = __fsqrt_rn(WIN_CUT / sd0);
        float r1 = __fsqrt_rn(WIN_CUT / sd1);
        lds_lo[i0] = m0 - r0; lds_hi[i0] = m0 + r0;
        lds_lo[i0 + 1] = m1 - r1; lds_hi[i0 + 1] = m1 + r1;
        out_mean[(size_t)sa * B_DIM + b] = m0;
        out_mean[(size_t)sb * B_DIM + b] = m1;
    }
    __syncthreads();
    if (tid == 0) {
        float lo = 1e30f, hi = -1e30f;
        #pragma unroll
        for (int i = 0; i < CH; ++i) {
            lo = fminf(lo, lds_lo[i]);
            hi = fmaxf(hi, lds_hi[i]);
        }
        int tlo = (int)floorf(lo);
        if (tlo < 0) tlo = 0; if (tlo > T_DIM - 1) tlo = T_DIM - 1;
        int thi = (int)ceilf(hi);
        if (thi > T_DIM - 1) thi = T_DIM - 1; if (thi < tlo) thi = tlo;
        s_tlo = tlo; s_thi = thi;
    }
    __syncthreads();
    const int tlo = s_tlo, thi = s_thi;

    v4f acc[8];
    #pragma unroll
    for (int i = 0; i < 8; ++i) acc[i] = (v4f)0.f;

    for (int tseg = tlo; tseg <= thi; tseg += TSEG) {
        // Weights: all 256 threads; thread covers toff = tid>>2, 4 i-slots.
        {
            const int toff = tid >> 2;
            const int ibase = (tid & 3) * 4;
            const int t = tseg + toff;
            float mv = 0.f;
            if (t <= thi) mv = mask[(size_t)t * B_DIM + b];
            v4f w;
            #pragma unroll
            for (int j = 0; j < 4; ++j) {
                int i = ibase + j;
                float d = lds_mean[i] - (float)t;
                w[j] = (t <= thi) ? __expf(-lds_std[i] * d * d) * mv : 0.f;
            }
            *(v4f*)(lds_w + toff * CH + ibase) = w;
        }
        __syncthreads();
        const int tend = (thi < tseg + TSEG - 1) ? thi : (tseg + TSEG - 1);
        const float* wbase = lds_w + half * 8;
        v4f v = ((const v4f*)(emb + ((size_t)tseg * B_DIM + b) * E_DIM))[htid];
        for (int t = tseg; t <= tend; ++t) {
            // 1-deep prefetch: next row load issues before this row's FMAs.
            const int tn = (t < tend) ? t + 1 : t;
            v4f vn = ((const v4f*)(emb + ((size_t)tn * B_DIM + b) * E_DIM))[htid];
            const float* wrow = wbase + (t - tseg) * CH;
            #pragma unroll
            for (int i = 0; i < 8; ++i) {
                float w = wrow[i];
                acc[i] += w * v;
            }
            v = vn;
        }
        __syncthreads();
    }
    #pragma unroll
    for (int i = 0; i < 8; ++i) {
        v4f* dst = (v4f*)(out + ((size_t)(s0 + half * 8 + i) * B_DIM + b) * E_DIM);
        __builtin_nontemporal_store(acc[i], dst + htid);  // write-once, bypass L2
    }
}

extern "C" void kernel_launch(void* const* d_in, const int* in_sizes, int n_in,
                              void* d_out, int out_size, void* d_ws, size_t ws_size,
                              hipStream_t stream) {
    const float* query = (const float*)d_in[0]; // [S,B,Q]
    const float* emb   = (const float*)d_in[1]; // [T,B,E]
    const float* mask  = (const float*)d_in[2]; // [T,B]
    const float* pos   = (const float*)d_in[3]; // [S,B]
    const float* W     = (const float*)d_in[4]; // [2,Q]
    const float* bias  = (const float*)d_in[5]; // [2]

    float* out_ctx  = (float*)d_out;                            // S*B*E
    float* out_mean = out_ctx + (size_t)S_DIM * B_DIM * E_DIM;  // S*B

    float* ws_mraw = (float*)d_ws;                      // [B,S]
    float* ws_std  = ws_mraw + (size_t)S_DIM * B_DIM;   // [B,S] (128 KiB total)

    dot_kernel<<<(S_DIM * B_DIM) / 4, 256, 0, stream>>>(query, W, bias, ws_mraw, ws_std);
    ctx_kernel<<<dim3(S_DIM / CH, B_DIM), 256, 0, stream>>>(
        emb, mask, ws_mraw, ws_std, pos, out_ctx, out_mean);
}